// Round 10
// baseline (1058.869 us; speedup 1.0000x reference)
//
#include <hip/hip_runtime.h>
#include <hip/hip_bf16.h>
#include <math.h>

#define NCH 64       // C
#define T_LEN 65536
#define NLAYER 18

typedef __attribute__((ext_vector_type(8))) short bf16x8;   // 8 bf16 = 4 VGPRs
typedef __attribute__((ext_vector_type(4))) short bf16x4;   // 4 bf16 = 2 VGPRs
typedef __attribute__((ext_vector_type(4))) float f32x4;

static __device__ __forceinline__ float bf2f(short s) {
    union { short u[2]; float f; } v;
    v.u[0] = 0; v.u[1] = s;
    return v.f;
}
static __device__ __forceinline__ short f2bf(float f) {
    __hip_bfloat16 h = __float2bfloat16(f);
    return *(short*)&h;
}

// ---------------------------------------------------------------------------
// whid[l][o][k]: k<64 -> hid_w[l][o][k][0] (past tap), k>=64 -> [k-64][1] (cur)
// ---------------------------------------------------------------------------
__global__ void convert_weights_kernel(const float* __restrict__ hid_w,
                                       const float* __restrict__ res_w,
                                       __hip_bfloat16* __restrict__ whid,
                                       __hip_bfloat16* __restrict__ wres) {
    int gid = blockIdx.x * 256 + threadIdx.x;
    if (gid < NLAYER * 128 * 128) {
        int l   = gid >> 14;
        int rem = gid & 16383;
        int o   = rem >> 7;
        int k   = rem & 127;
        float v = (k < 64)
            ? hid_w[((l * 128 + o) * 64 + k) * 2]
            : hid_w[((l * 128 + o) * 64 + (k - 64)) * 2 + 1];
        whid[gid] = __float2bfloat16(v);
    }
    if (gid < NLAYER * 64 * 64) {
        wres[gid] = __float2bfloat16(res_w[gid]);
    }
}

// ---------------------------------------------------------------------------
// Fused 6-layer pass -- R2 structure (VGPR 84 at (256,3), 3 blocks/CU,
// occ 28%, no spill) + ROUND-10 DEAD-HALO-TILE SKIPPING.
//
// Validity-edge fact: after layer l (d=2^l), only rows >= E_l = 2^(l+1) are
// consumed downstream (row t needs inputs t, t-d >= E_{l-1}; staging covers
// E_{-1}=0). Tiles (16 rows) fully below E_l are skipped for GEMM1 + gate +
// GEMM2 + epilogue: layer 3 skips 1 tile, layer 4 skips 2, layer 5 skips 4
// (whole chunk 0) -- 7/72 tiles ~ 10% of MFMA+gate work, as a wave-uniform
// branch (nt >= d/8 in chunk 0). Tile alignment exact: first kept tile's
// past-taps land at E_{l-1}.
//
// VGPR-BUDGET RULE (calibrated R3/R4/R8): budget = 256/arg2 regardless of
// block size. >85 live regs => spill at 3 waves/SIMD (R7/R8 disaster).
//
// LDS: A/G [192][64] bf16, XOR swizzle col ^= (row&7)<<3 (bank-minimal).
// Gate: tanh(x)*sigmoid(y) = (e^2x-1)/((e^2x+1)(1+e^-y)) -- one rcp.
// Skip->mix in registers, one reduce at kernel end via shfl + skbuf over G.
// ---------------------------------------------------------------------------
__global__ __launch_bounds__(256, 3) void fused6_kernel(
    const void* __restrict__ src,                 // fp32 x | bf16 prev
    __hip_bfloat16* __restrict__ next,            // [B][T][C]
    float* __restrict__ acc,                      // [B][T]
    const __hip_bfloat16* __restrict__ whid_all,  // [18][128][128]
    const float* __restrict__ hb_all,             // [18][128]
    const __hip_bfloat16* __restrict__ wres_all,  // [18][64][64]
    const float* __restrict__ rb_all,             // [18][64]
    const float* __restrict__ mix_w,              // [1152]
    const float* __restrict__ in_w,               // [64]
    const float* __restrict__ in_b,               // [64]
    int lbase, int is_first) {
    __shared__ __align__(16) __hip_bfloat16 A[192 * 64];
    __shared__ __align__(16) __hip_bfloat16 G[192 * 64];

#define SW(row, col) ((row) * 64 + ((col) ^ (((row) & 7) << 3)))

    const int b    = blockIdx.x >> 9;          // 512 windows per batch
    const int widx = blockIdx.x & 511;
    const int t0   = widx << 7;
    const int tw   = t0 - 64;

    const int tid  = threadIdx.x;
    const int lane = tid & 63;
    const int w4   = tid >> 6;
    const int l15  = lane & 15;
    const int quad = lane >> 4;
    const int m0   = w4 * 16;
    const int rr   = tid >> 3;                 // 0..31
    const int co   = (tid & 7) * 8;

    // ---- stage input window [tw, tw+192) ----
    if (is_first) {
        const float* x = (const float*)src;
        float iw[8], ib[8];
#pragma unroll
        for (int j = 0; j < 8; ++j) { iw[j] = in_w[co + j]; ib[j] = in_b[co + j]; }
#pragma unroll
        for (int round = 0; round < 6; ++round) {
            int r  = round * 32 + rr;
            int gt = tw + r;
            bf16x8 v = {0, 0, 0, 0, 0, 0, 0, 0};
            if (gt >= 0) {
                float xv = x[(size_t)b * T_LEN + gt];
#pragma unroll
                for (int j = 0; j < 8; ++j) v[j] = f2bf(iw[j] * xv + ib[j]);
            }
            *(bf16x8*)(&A[SW(r, co)]) = v;
        }
    } else {
        const __hip_bfloat16* prev = (const __hip_bfloat16*)src;
#pragma unroll
        for (int round = 0; round < 6; ++round) {
            int r  = round * 32 + rr;
            int gt = tw + r;
            bf16x8 v = {0, 0, 0, 0, 0, 0, 0, 0};
            if (gt >= 0)
                v = *(const bf16x8*)(prev + ((size_t)b * T_LEN + gt) * NCH + co);
            *(bf16x8*)(&A[SW(r, co)]) = v;
        }
    }

    // per-thread skip partials for the 8 owned output rows
    // index (ct-1)*4 + nt  ->  row = ct*64 + nt*16 + l15, ct in {1,2}
    float skp[8] = {0.f, 0.f, 0.f, 0.f, 0.f, 0.f, 0.f, 0.f};

#pragma unroll 1
    for (int l = 0; l < 6; ++l) {
        const int d = 1 << l;
        const int ntS = d >> 3;   // chunk-0 tiles nt < ntS are fully below
                                  // the validity edge E_l = 2d -> skip
        const __hip_bfloat16* whid = whid_all + (size_t)(lbase + l) * 16384;
        const __hip_bfloat16* wres = wres_all + (size_t)(lbase + l) * 4096;
        const float* hb = hb_all + (lbase + l) * 128;
        const float* rb = rb_all + (lbase + l) * 64;
        const float* mw = mix_w + (lbase + l) * 64;

        // ---- per-layer weights to registers ----
        bf16x8 aT[4], aS[4], aR[2];
        {
            const __hip_bfloat16* whT = whid + (size_t)(m0 + l15) * 128 + quad * 8;
            const __hip_bfloat16* whS = whT + 64 * 128;
#pragma unroll
            for (int k = 0; k < 4; ++k) {
                aT[k] = *(const bf16x8*)(whT + k * 32);
                aS[k] = *(const bf16x8*)(whS + k * 32);
            }
            const __hip_bfloat16* wrA = wres + (size_t)(m0 + l15) * 64 + quad * 8;
            aR[0] = *(const bf16x8*)(wrA);
            aR[1] = *(const bf16x8*)(wrA + 32);
        }
        f32x4 biasT, biasS, biasR;
#pragma unroll
        for (int r = 0; r < 4; ++r) {
            biasT[r] = hb[m0 + quad * 4 + r];
            biasS[r] = hb[64 + m0 + quad * 4 + r];
            biasR[r] = rb[m0 + quad * 4 + r];
        }
        // own-channel mix weights (4 floats, 16B-aligned)
        f32x4 mw4 = *(const f32x4*)(mw + m0 + quad * 4);

        __syncthreads();   // staging / previous epilogue A-writes visible

        // ---- phase 1: GEMM1 + gate, all 3 chunks of 64 t ----
#pragma unroll
        for (int ct = 0; ct < 3; ++ct) {
            const int n0 = (ct == 0) ? ntS : 0;   // wave-uniform skip bound
            f32x4 accT[4], accS[4];
#pragma unroll
            for (int nt = 0; nt < 4; ++nt) { accT[nt] = biasT; accS[nt] = biasS; }
#pragma unroll
            for (int ks = 0; ks < 4; ++ks) {
                const int koff = (ks & 1) * 32 + quad * 8;
#pragma unroll
                for (int nt = 0; nt < 4; ++nt) {
                    if (nt >= n0) {
                        int trow = ct * 64 + nt * 16 + l15;
                        int prow = trow - d;  prow = prow < 0 ? 0 : prow;
                        int row  = (ks < 2) ? prow : trow;
                        bf16x8 bx = *(const bf16x8*)(&A[SW(row, koff)]);
                        accT[nt] = __builtin_amdgcn_mfma_f32_16x16x32_bf16(aT[ks], bx, accT[nt], 0, 0, 0);
                        accS[nt] = __builtin_amdgcn_mfma_f32_16x16x32_bf16(aS[ks], bx, accS[nt], 0, 0, 0);
                    }
                }
            }
#pragma unroll
            for (int nt = 0; nt < 4; ++nt) {
                if (nt >= n0) {
                    int trow = ct * 64 + nt * 16 + l15;
                    bf16x4 gv;
                    float gsum = 0.f;
#pragma unroll
                    for (int r = 0; r < 4; ++r) {
                        // tanh(x)*sigmoid(y) = (e^2x - 1) / ((e^2x + 1)(1 + e^-y))
                        float ea = __expf(2.f * accT[nt][r]);
                        float eb = __expf(-accS[nt][r]);
                        float g  = (ea - 1.f) *
                                   __builtin_amdgcn_rcpf((ea + 1.f) * (1.f + eb));
                        gsum += mw4[r] * g;
                        gv[r] = f2bf(g);
                    }
                    if (ct >= 1) skp[(ct - 1) * 4 + nt] += gsum;
                    *(bf16x4*)(&G[SW(trow, m0 + quad * 4)]) = gv;
                }
            }
        }
        __syncthreads();  // G complete, all A-reads of GEMM1 done

        // ---- phase 2: GEMM2 + in-place residual epilogue ----
#pragma unroll
        for (int ct = 0; ct < 3; ++ct) {
            const int n0 = (ct == 0) ? ntS : 0;
            f32x4 accR[4];
#pragma unroll
            for (int nt = 0; nt < 4; ++nt) accR[nt] = biasR;
#pragma unroll
            for (int ks = 0; ks < 2; ++ks) {
                const int koff = ks * 32 + quad * 8;
#pragma unroll
                for (int nt = 0; nt < 4; ++nt) {
                    if (nt >= n0) {
                        int trow = ct * 64 + nt * 16 + l15;
                        bf16x8 bx = *(const bf16x8*)(&G[SW(trow, koff)]);
                        accR[nt] = __builtin_amdgcn_mfma_f32_16x16x32_bf16(aR[ks], bx, accR[nt], 0, 0, 0);
                    }
                }
            }
#pragma unroll
            for (int nt = 0; nt < 4; ++nt) {
                if (nt >= n0) {
                    int trow = ct * 64 + nt * 16 + l15;
                    bf16x4 old = *(const bf16x4*)(&A[SW(trow, m0 + quad * 4)]);
                    bool ok = (tw + trow) >= 0;   // causal zero for global t<0
                    bf16x4 ov;
#pragma unroll
                    for (int r = 0; r < 4; ++r) {
                        float v = accR[nt][r] + bf2f(old[r]);
                        ov[r] = f2bf(ok ? v : 0.f);
                    }
                    *(bf16x4*)(&A[SW(trow, m0 + quad * 4)]) = ov;
                }
            }
        }
    }
    __syncthreads();  // last epilogue visible, last G reads done

    // ---- write output window [t0, t0+128) ----
#pragma unroll
    for (int round = 0; round < 4; ++round) {
        int pr = round * 32 + rr;
        *(bf16x8*)(next + ((size_t)b * T_LEN + t0 + pr) * NCH + co) =
            *(const bf16x8*)(&A[SW(pr + 64, co)]);
    }

    // ---- skip: quad-reduce in-wave, cross-wave via skbuf (overlays G) ----
    float* skbuf = (float*)G;   // [4][128] = 2 KB, G is dead now
#pragma unroll
    for (int i = 0; i < 8; ++i) {
        skp[i] += __shfl_xor(skp[i], 16, 64);
        skp[i] += __shfl_xor(skp[i], 32, 64);
    }
    if (quad == 0) {
#pragma unroll
        for (int i = 0; i < 8; ++i) {
            int ct = i >> 2, nt = i & 3;
            skbuf[w4 * 128 + ct * 64 + nt * 16 + l15] = skp[i];
        }
    }
    __syncthreads();
    if (tid < 128) {
        float tot = skbuf[tid] + skbuf[128 + tid] +
                    skbuf[256 + tid] + skbuf[384 + tid];
        acc[(size_t)b * T_LEN + t0 + tid] += tot;
    }
#undef SW
}

// ---------------------------------------------------------------------------
// Single-layer pass (R9 low-VGPR version -- kept: passed, tail declared
// dependency-bound/converged per R9 decision rule).
// ---------------------------------------------------------------------------
__global__ __launch_bounds__(256, 3) void layer_mfma_kernel(
    const __hip_bfloat16* __restrict__ prev,   // [B][T][C] bf16
    __hip_bfloat16* __restrict__ next,         // [B][T][C] bf16
    float* __restrict__ acc,                   // [B][T]
    const __hip_bfloat16* __restrict__ whid,   // [128][128] this layer
    const float* __restrict__ hb,              // [128]
    const __hip_bfloat16* __restrict__ wres,   // [64][64]
    const float* __restrict__ rb,              // [64]
    const float* __restrict__ mw,              // [64]
    int d) {
    __shared__ __align__(16) __hip_bfloat16 Xp[64 * 72];
    __shared__ __align__(16) __hip_bfloat16 Xc[64 * 72];
    __shared__ __align__(16) __hip_bfloat16 Gt[64 * 72];
    __shared__ float skb[4 * 64];   // 1 KB; total LDS 28.7 KB

    const int t0   = blockIdx.x << 6;
    const int tid  = threadIdx.x;
    const int lane = tid & 63;
    const int w4   = tid >> 6;
    const int l15  = lane & 15;
    const int quad = lane >> 4;
    const int m0   = w4 * 16;
    const int rr = tid >> 3;
    const int co = (tid & 7) * 8;

    bf16x8 aT[4], aS[4];
    {
        const __hip_bfloat16* whT = whid + (size_t)(m0 + l15) * 128 + quad * 8;
        const __hip_bfloat16* whS = whT + 64 * 128;
#pragma unroll
        for (int k = 0; k < 4; ++k) {
            aT[k] = *(const bf16x8*)(whT + k * 32);
            aS[k] = *(const bf16x8*)(whS + k * 32);
        }
    }
    f32x4 biasT, biasS;
#pragma unroll
    for (int r = 0; r < 4; ++r) {
        biasT[r] = hb[m0 + quad * 4 + r];
        biasS[r] = hb[64 + m0 + quad * 4 + r];
    }
    f32x4 mw4 = *(const f32x4*)(mw + m0 + quad * 4);

#pragma unroll 1
    for (int b = 0; b < 4; ++b) {
        // ---- stage (no prefetch; latency hidden by co-resident blocks) ----
        {
            const __hip_bfloat16* pb = prev + ((size_t)b * T_LEN + t0) * NCH;
#pragma unroll
            for (int pass = 0; pass < 2; ++pass) {
                int r = pass * 32 + rr;
                bf16x8 vc = *(const bf16x8*)(pb + r * NCH + co);
                int tp = t0 + r - d;
                bf16x8 vp = {0, 0, 0, 0, 0, 0, 0, 0};
                if (tp >= 0)
                    vp = *(const bf16x8*)(prev + ((size_t)b * T_LEN + tp) * NCH + co);
                *(bf16x8*)(&Xc[r * 72 + co]) = vc;
                *(bf16x8*)(&Xp[r * 72 + co]) = vp;
            }
        }
        __syncthreads();                       // barrier A

        // ---- GEMM1 + gate + in-register skip, in nt-pairs ----
        float sk[4];
#pragma unroll
        for (int np = 0; np < 2; ++np) {
            f32x4 accT[2], accS[2];
#pragma unroll
            for (int h = 0; h < 2; ++h) { accT[h] = biasT; accS[h] = biasS; }
#pragma unroll
            for (int ks = 0; ks < 4; ++ks) {
                const __hip_bfloat16* srcb = (ks < 2) ? Xp : Xc;
                const int kk = (ks & 1) * 32 + quad * 8;
#pragma unroll
                for (int h = 0; h < 2; ++h) {
                    int nt = np * 2 + h;
                    bf16x8 bx = *(const bf16x8*)(&srcb[(nt * 16 + l15) * 72 + kk]);
                    accT[h] = __builtin_amdgcn_mfma_f32_16x16x32_bf16(aT[ks], bx, accT[h], 0, 0, 0);
                    accS[h] = __builtin_amdgcn_mfma_f32_16x16x32_bf16(aS[ks], bx, accS[h], 0, 0, 0);
                }
            }
#pragma unroll
            for (int h = 0; h < 2; ++h) {
                int nt = np * 2 + h;
                float gsum = 0.f;
#pragma unroll
                for (int r = 0; r < 4; ++r) {
                    float ea = __expf(2.f * accT[h][r]);
                    float eb = __expf(-accS[h][r]);
                    float g  = (ea - 1.f) *
                               __builtin_amdgcn_rcpf((ea + 1.f) * (1.f + eb));
                    gsum += mw4[r] * g;
                    Gt[(nt * 16 + l15) * 72 + m0 + quad * 4 + r] = __float2bfloat16(g);
                }
                sk[nt] = gsum;
            }
        }
        // skip: reduce over quad (16 channels), write per-wave partial
#pragma unroll
        for (int nt = 0; nt < 4; ++nt) {
            sk[nt] += __shfl_xor(sk[nt], 16, 64);
            sk[nt] += __shfl_xor(sk[nt], 32, 64);
        }
        if (quad == 0) {
#pragma unroll
            for (int nt = 0; nt < 4; ++nt)
                skb[w4 * 64 + nt * 16 + l15] = sk[nt];
        }

        bf16x4 curres[4];
#pragma unroll
        for (int nt = 0; nt < 4; ++nt) {
            curres[nt] = *(const bf16x4*)(&Xc[(nt * 16 + l15) * 72 + m0 + quad * 4]);
        }
        __syncthreads();                       // barrier B (Gt + skb visible)

        // ---- deferred res-conv weights (L2-hot reload per batch) ----
        bf16x8 aR0, aR1;
        {
            const __hip_bfloat16* wrA = wres + (size_t)(m0 + l15) * 64 + quad * 8;
            aR0 = *(const bf16x8*)(wrA);
            aR1 = *(const bf16x8*)(wrA + 32);
        }
        f32x4 biasR;
#pragma unroll
        for (int r = 0; r < 4; ++r) biasR[r] = rb[m0 + quad * 4 + r];

        f32x4 accR[4];
#pragma unroll
        for (int nt = 0; nt < 4; ++nt) accR[nt] = biasR;
#pragma unroll
        for (int ks = 0; ks < 2; ++ks) {
            const int kk = ks * 32 + quad * 8;
#pragma unroll
            for (int nt = 0; nt < 4; ++nt) {
                bf16x8 bx = *(const bf16x8*)(&Gt[(nt * 16 + l15) * 72 + kk]);
                accR[nt] = __builtin_amdgcn_mfma_f32_16x16x32_bf16(
                    (ks == 0) ? aR0 : aR1, bx, accR[nt], 0, 0, 0);
            }
        }

        __hip_bfloat16* nb = next + ((size_t)b * T_LEN + t0) * NCH;
#pragma unroll
        for (int nt = 0; nt < 4; ++nt) {
            int t = nt * 16 + l15;
            bf16x4 ov;
#pragma unroll
            for (int r = 0; r < 4; ++r) {
                ov[r] = f2bf(accR[nt][r] + bf2f(curres[nt][r]));
            }
            *(bf16x4*)(nb + t * NCH + m0 + quad * 4) = ov;
        }

        // ---- skip finalize: sum 4 wave-partials, one RMW per t ----
        if (tid < 64) {
            float tot = skb[tid] + skb[64 + tid] + skb[128 + tid] + skb[192 + tid];
            acc[(size_t)b * T_LEN + t0 + tid] += tot;
        }
        // next iteration's skb writes are after barrier A(b+1) -> no race
    }
}

// ---------------------------------------------------------------------------
// Last layer (17, d=256): GEMM1 + gate + skip only (res-conv output unused),
// fused finalize: out = acc + own skip + mix_b. No next write. (R2 config.)
// ---------------------------------------------------------------------------
__global__ __launch_bounds__(256, 2) void last_layer_kernel(
    const __hip_bfloat16* __restrict__ prev,   // [B][T][C]
    const float* __restrict__ acc,             // [B][T] (layers 0..16 summed)
    float* __restrict__ out,                   // [B][T] fp32
    const __hip_bfloat16* __restrict__ whid,   // [128][128] layer 17
    const float* __restrict__ hb,              // [128]
    const float* __restrict__ mw,              // [64] layer-17 mix slice
    const float* __restrict__ mix_b,           // [1]
    int d) {
    __shared__ __align__(16) __hip_bfloat16 Xp[64 * 72];
    __shared__ __align__(16) __hip_bfloat16 Xc[64 * 72];
    __shared__ float skb[4 * 64];

    const int t0   = blockIdx.x << 6;
    const int tid  = threadIdx.x;
    const int lane = tid & 63;
    const int w4   = tid >> 6;
    const int l15  = lane & 15;
    const int quad = lane >> 4;
    const int m0   = w4 * 16;
    const int rr = tid >> 3;
    const int co = (tid & 7) * 8;

    bf16x8 aT[4], aS[4];
    {
        const __hip_bfloat16* whT = whid + (size_t)(m0 + l15) * 128 + quad * 8;
        const __hip_bfloat16* whS = whT + 64 * 128;
#pragma unroll
        for (int k = 0; k < 4; ++k) {
            aT[k] = *(const bf16x8*)(whT + k * 32);
            aS[k] = *(const bf16x8*)(whS + k * 32);
        }
    }
    f32x4 biasT, biasS;
    float mwv[4];
#pragma unroll
    for (int r = 0; r < 4; ++r) {
        biasT[r] = hb[m0 + quad * 4 + r];
        biasS[r] = hb[64 + m0 + quad * 4 + r];
        mwv[r]   = mw[m0 + quad * 4 + r];
    }
    const float mb = mix_b[0];

    bf16x8 pc[2], pp[2];
#define LOAD_TILE(b)                                                          \
    do {                                                                      \
        const __hip_bfloat16* pb = prev + ((size_t)(b) * T_LEN + t0) * NCH;   \
        _Pragma("unroll")                                                     \
        for (int pass = 0; pass < 2; ++pass) {                                \
            int r = pass * 32 + rr;                                           \
            pc[pass] = *(const bf16x8*)(pb + r * NCH + co);                   \
            int tp = t0 + r - d;                                              \
            bf16x8 z = {0, 0, 0, 0, 0, 0, 0, 0};                              \
            pp[pass] = z;                                                     \
            if (tp >= 0)                                                      \
                pp[pass] = *(const bf16x8*)(prev +                            \
                    ((size_t)(b) * T_LEN + tp) * NCH + co);                   \
        }                                                                     \
    } while (0)

    LOAD_TILE(0);

#pragma unroll
    for (int b = 0; b < 4; ++b) {
#pragma unroll
        for (int pass = 0; pass < 2; ++pass) {
            int r = pass * 32 + rr;
            *(bf16x8*)(&Xc[r * 72 + co]) = pc[pass];
            *(bf16x8*)(&Xp[r * 72 + co]) = pp[pass];
        }
        __syncthreads();                       // barrier A

        if (b < 3) LOAD_TILE(b + 1);

        f32x4 accT[4], accS[4];
#pragma unroll
        for (int nt = 0; nt < 4; ++nt) { accT[nt] = biasT; accS[nt] = biasS; }
#pragma unroll
        for (int ks = 0; ks < 4; ++ks) {
            const __hip_bfloat16* srcb = (ks < 2) ? Xp : Xc;
            const int kk = (ks & 1) * 32 + quad * 8;
#pragma unroll
            for (int nt = 0; nt < 4; ++nt) {
                bf16x8 bx = *(const bf16x8*)(&srcb[(nt * 16 + l15) * 72 + kk]);
                accT[nt] = __builtin_amdgcn_mfma_f32_16x16x32_bf16(aT[ks], bx, accT[nt], 0, 0, 0);
                accS[nt] = __builtin_amdgcn_mfma_f32_16x16x32_bf16(aS[ks], bx, accS[nt], 0, 0, 0);
            }
        }

        // gate + skip partial (no Gt/GEMM2 needed for last layer)
#pragma unroll
        for (int nt = 0; nt < 4; ++nt) {
            float sv = 0.f;
#pragma unroll
            for (int r = 0; r < 4; ++r) {
                float e2 = __expf(2.f * accT[nt][r]);
                float th = 1.f - 2.f * __builtin_amdgcn_rcpf(e2 + 1.f);
                float sg = __builtin_amdgcn_rcpf(1.f + __expf(-accS[nt][r]));
                sv += mwv[r] * (th * sg);
            }
            sv += __shfl_xor(sv, 16, 64);
            sv += __shfl_xor(sv, 32, 64);
            if (quad == 0)
                skb[w4 * 64 + nt * 16 + l15] = sv;
        }
        __syncthreads();                       // barrier B

        if (tid < 64) {
            float tot = skb[tid] + skb[64 + tid] + skb[128 + tid] + skb[192 + tid];
            out[(size_t)b * T_LEN + t0 + tid] =
                acc[(size_t)b * T_LEN + t0 + tid] + tot + mb;
        }
    }
#undef LOAD_TILE
}

// ---------------------------------------------------------------------------
extern "C" void kernel_launch(void* const* d_in, const int* in_sizes, int n_in,
                              void* d_out, int out_size, void* d_ws, size_t ws_size,
                              hipStream_t stream) {
    const float* x     = (const float*)d_in[0];
    const float* in_w  = (const float*)d_in[1];
    const float* in_b  = (const float*)d_in[2];
    const float* hid_w = (const float*)d_in[3];  // [18][128][64][2]
    const float* hid_b = (const float*)d_in[4];  // [18][128]
    const float* res_w = (const float*)d_in[5];  // [18][64][64][1]
    const float* res_b = (const float*)d_in[6];  // [18][64]
    const float* mix_w = (const float*)d_in[7];  // [1152]
    const float* mix_b = (const float*)d_in[8];  // [1]
    float* out = (float*)d_out;

    // ws layout: actA 32M | actB 32M | acc 1M | whid 0.56M | wres 0.14M
    const size_t act_elems = 4ull * T_LEN * NCH;     // 16M bf16 = 32 MB
    __hip_bfloat16* actA = (__hip_bfloat16*)d_ws;
    __hip_bfloat16* actB = actA + act_elems;
    float* acc = (float*)(actB + act_elems);         // [B][T] = 1 MB
    __hip_bfloat16* whid = (__hip_bfloat16*)(acc + 4ull * T_LEN);
    __hip_bfloat16* wres = whid + (size_t)NLAYER * 128 * 128;

    hipMemsetAsync(acc, 0, 4ull * T_LEN * sizeof(float), stream);

    convert_weights_kernel<<<1152, 256, 0, stream>>>(hid_w, res_w, whid, wres);

    // P0: input conv + layers 0-5 (d=1..32) fused -> actA
    fused6_kernel<<<2048, 256, 0, stream>>>(
        x, actA, acc, whid, hid_b, wres, res_b, mix_w, in_w, in_b, 0, 1);

    // P1-P3: layers 6,7,8 (d=64,128,256)
    layer_mfma_kernel<<<1024, 256, 0, stream>>>(
        actA, actB, acc, whid + 6 * 16384, hid_b + 6 * 128,
        wres + 6 * 4096, res_b + 6 * 64, mix_w + 6 * 64, 64);
    layer_mfma_kernel<<<1024, 256, 0, stream>>>(
        actB, actA, acc, whid + 7 * 16384, hid_b + 7 * 128,
        wres + 7 * 4096, res_b + 7 * 64, mix_w + 7 * 64, 128);
    layer_mfma_kernel<<<1024, 256, 0, stream>>>(
        actA, actB, acc, whid + 8 * 16384, hid_b + 8 * 128,
        wres + 8 * 4096, res_b + 8 * 64, mix_w + 8 * 64, 256);

    // P4: layers 9-14 (d=1..32) fused -> actA
    fused6_kernel<<<2048, 256, 0, stream>>>(
        actB, actA, acc, whid, hid_b, wres, res_b, mix_w, in_w, in_b, 9, 0);

    // P5-P6: layers 15,16 (d=64,128)
    layer_mfma_kernel<<<1024, 256, 0, stream>>>(
        actA, actB, acc, whid + 15 * 16384, hid_b + 15 * 128,
        wres + 15 * 4096, res_b + 15 * 64, mix_w + 15 * 64, 64);
    layer_mfma_kernel<<<1024, 256, 0, stream>>>(
        actB, actA, acc, whid + 16 * 16384, hid_b + 16 * 128,
        wres + 16 * 4096, res_b + 16 * 64, mix_w + 16 * 64, 128);

    // P7: layer 17 (d=256) + finalize -> out
    last_layer_kernel<<<1024, 256, 0, stream>>>(
        actA, acc, out, whid + 17 * 16384, hid_b + 17 * 128,
        mix_w + 17 * 64, mix_b, 256);
}

// Round 11
// 489.390 us; speedup vs baseline: 2.1636x; 2.1636x over previous
//
#include <hip/hip_runtime.h>
#include <hip/hip_bf16.h>
#include <math.h>

#define NCH 64       // C
#define T_LEN 65536
#define NLAYER 18

typedef __attribute__((ext_vector_type(8))) short bf16x8;   // 8 bf16 = 4 VGPRs
typedef __attribute__((ext_vector_type(4))) short bf16x4;   // 4 bf16 = 2 VGPRs
typedef __attribute__((ext_vector_type(4))) float f32x4;

static __device__ __forceinline__ float bf2f(short s) {
    union { short u[2]; float f; } v;
    v.u[0] = 0; v.u[1] = s;
    return v.f;
}
static __device__ __forceinline__ short f2bf(float f) {
    __hip_bfloat16 h = __float2bfloat16(f);
    return *(short*)&h;
}

// ---------------------------------------------------------------------------
// whid[l][o][k]: k<64 -> hid_w[l][o][k][0] (past tap), k>=64 -> [k-64][1] (cur)
// ---------------------------------------------------------------------------
__global__ void convert_weights_kernel(const float* __restrict__ hid_w,
                                       const float* __restrict__ res_w,
                                       __hip_bfloat16* __restrict__ whid,
                                       __hip_bfloat16* __restrict__ wres) {
    int gid = blockIdx.x * 256 + threadIdx.x;
    if (gid < NLAYER * 128 * 128) {
        int l   = gid >> 14;
        int rem = gid & 16383;
        int o   = rem >> 7;
        int k   = rem & 127;
        float v = (k < 64)
            ? hid_w[((l * 128 + o) * 64 + k) * 2]
            : hid_w[((l * 128 + o) * 64 + (k - 64)) * 2 + 1];
        whid[gid] = __float2bfloat16(v);
    }
    if (gid < NLAYER * 64 * 64) {
        wres[gid] = __float2bfloat16(res_w[gid]);
    }
}

// ---------------------------------------------------------------------------
// Fused 6-layer pass -- R2/R9 structure (VGPR 84 at (256,3), 3 blocks/CU,
// occ 28%, no spill) + ROUND-11 dead-halo skip via STATIC VARIANTS.
//
// Validity edge: after layer l (d=2^l) only rows >= E_l = 2^(l+1) are
// consumed downstream (row t needs t, t-d >= E_{l-1}; E_{-1}=0 at staging).
// Chunk-0 tiles below the edge are skipped: layer 3 skips 1 tile, layer 4
// skips 2, layer 5 skips chunk 0 entirely -- 7/72 tiles ~ 10% of MFMA+gate.
//
// R10 LESSON: runtime `if (nt >= n0)` guards inside the unrolled MFMA loops
// created conditional acc liveness -> spill at the 85-reg budget (WRITE
// 898 MB scratch, 446us). Fix: THREE compile-time chunk-0 variants
// (N0 = 0/1/2 as macro literals; layer 5 skips the call) selected by ONE
// wave-uniform scalar branch on d. Each variant is a static subset of the
// proven R9 body -- no conditional liveness, no dynamic indexing.
//
// VGPR-BUDGET RULE (R3/R4/R8): budget = 256/arg2 regardless of block size.
// LDS: A/G [192][64] bf16, XOR swizzle col ^= (row&7)<<3 (bank-minimal).
// Gate: tanh(x)*sigmoid(y) = (e^2x-1)/((e^2x+1)(1+e^-y)) -- one rcp.
// Skip->mix in registers, one reduce at kernel end via shfl + skbuf over G.
// ---------------------------------------------------------------------------
__global__ __launch_bounds__(256, 3) void fused6_kernel(
    const void* __restrict__ src,                 // fp32 x | bf16 prev
    __hip_bfloat16* __restrict__ next,            // [B][T][C]
    float* __restrict__ acc,                      // [B][T]
    const __hip_bfloat16* __restrict__ whid_all,  // [18][128][128]
    const float* __restrict__ hb_all,             // [18][128]
    const __hip_bfloat16* __restrict__ wres_all,  // [18][64][64]
    const float* __restrict__ rb_all,             // [18][64]
    const float* __restrict__ mix_w,              // [1152]
    const float* __restrict__ in_w,               // [64]
    const float* __restrict__ in_b,               // [64]
    int lbase, int is_first) {
    __shared__ __align__(16) __hip_bfloat16 A[192 * 64];
    __shared__ __align__(16) __hip_bfloat16 G[192 * 64];

#define SW(row, col) ((row) * 64 + ((col) ^ (((row) & 7) << 3)))

    const int b    = blockIdx.x >> 9;          // 512 windows per batch
    const int widx = blockIdx.x & 511;
    const int t0   = widx << 7;
    const int tw   = t0 - 64;

    const int tid  = threadIdx.x;
    const int lane = tid & 63;
    const int w4   = tid >> 6;
    const int l15  = lane & 15;
    const int quad = lane >> 4;
    const int m0   = w4 * 16;
    const int rr   = tid >> 3;                 // 0..31
    const int co   = (tid & 7) * 8;

    // ---- stage input window [tw, tw+192) ----
    if (is_first) {
        const float* x = (const float*)src;
        float iw[8], ib[8];
#pragma unroll
        for (int j = 0; j < 8; ++j) { iw[j] = in_w[co + j]; ib[j] = in_b[co + j]; }
#pragma unroll
        for (int round = 0; round < 6; ++round) {
            int r  = round * 32 + rr;
            int gt = tw + r;
            bf16x8 v = {0, 0, 0, 0, 0, 0, 0, 0};
            if (gt >= 0) {
                float xv = x[(size_t)b * T_LEN + gt];
#pragma unroll
                for (int j = 0; j < 8; ++j) v[j] = f2bf(iw[j] * xv + ib[j]);
            }
            *(bf16x8*)(&A[SW(r, co)]) = v;
        }
    } else {
        const __hip_bfloat16* prev = (const __hip_bfloat16*)src;
#pragma unroll
        for (int round = 0; round < 6; ++round) {
            int r  = round * 32 + rr;
            int gt = tw + r;
            bf16x8 v = {0, 0, 0, 0, 0, 0, 0, 0};
            if (gt >= 0)
                v = *(const bf16x8*)(prev + ((size_t)b * T_LEN + gt) * NCH + co);
            *(bf16x8*)(&A[SW(r, co)]) = v;
        }
    }

    // per-thread skip partials for the 8 owned output rows
    // index (ct-1)*4 + nt  ->  row = ct*64 + nt*16 + l15, ct in {1,2}
    float skp[8] = {0.f, 0.f, 0.f, 0.f, 0.f, 0.f, 0.f, 0.f};

// ---- GEMM1+gate, chunk 0, tiles nt = N0..3 (N0 is a macro LITERAL) ----
#define G1_CHUNK0(N0)                                                         \
    do {                                                                      \
        f32x4 accT[4], accS[4];                                               \
        _Pragma("unroll")                                                     \
        for (int nt = N0; nt < 4; ++nt) { accT[nt] = biasT; accS[nt] = biasS; } \
        _Pragma("unroll")                                                     \
        for (int ks = 0; ks < 4; ++ks) {                                      \
            const int koff = (ks & 1) * 32 + quad * 8;                        \
            _Pragma("unroll")                                                 \
            for (int nt = N0; nt < 4; ++nt) {                                 \
                int trow = nt * 16 + l15;                                     \
                int prow = trow - d;  prow = prow < 0 ? 0 : prow;             \
                int row  = (ks < 2) ? prow : trow;                            \
                bf16x8 bx = *(const bf16x8*)(&A[SW(row, koff)]);              \
                accT[nt] = __builtin_amdgcn_mfma_f32_16x16x32_bf16(           \
                    aT[ks], bx, accT[nt], 0, 0, 0);                           \
                accS[nt] = __builtin_amdgcn_mfma_f32_16x16x32_bf16(           \
                    aS[ks], bx, accS[nt], 0, 0, 0);                           \
            }                                                                 \
        }                                                                     \
        _Pragma("unroll")                                                     \
        for (int nt = N0; nt < 4; ++nt) {                                     \
            int trow = nt * 16 + l15;                                         \
            bf16x4 gv;                                                        \
            _Pragma("unroll")                                                 \
            for (int r = 0; r < 4; ++r) {                                     \
                float ea = __expf(2.f * accT[nt][r]);                         \
                float eb = __expf(-accS[nt][r]);                              \
                float g  = (ea - 1.f) *                                       \
                           __builtin_amdgcn_rcpf((ea + 1.f) * (1.f + eb));    \
                gv[r] = f2bf(g);                                              \
            }                                                                 \
            *(bf16x4*)(&G[SW(trow, m0 + quad * 4)]) = gv;                     \
        }                                                                     \
    } while (0)

// ---- GEMM1+gate+skip, full chunk CT in {1,2} ----
#define G1_CHUNK_FULL(CT)                                                     \
    do {                                                                      \
        f32x4 accT[4], accS[4];                                               \
        _Pragma("unroll")                                                     \
        for (int nt = 0; nt < 4; ++nt) { accT[nt] = biasT; accS[nt] = biasS; } \
        _Pragma("unroll")                                                     \
        for (int ks = 0; ks < 4; ++ks) {                                      \
            const int koff = (ks & 1) * 32 + quad * 8;                        \
            _Pragma("unroll")                                                 \
            for (int nt = 0; nt < 4; ++nt) {                                  \
                int trow = (CT) * 64 + nt * 16 + l15;                         \
                int row  = (ks < 2) ? (trow - d) : trow;                      \
                bf16x8 bx = *(const bf16x8*)(&A[SW(row, koff)]);              \
                accT[nt] = __builtin_amdgcn_mfma_f32_16x16x32_bf16(           \
                    aT[ks], bx, accT[nt], 0, 0, 0);                           \
                accS[nt] = __builtin_amdgcn_mfma_f32_16x16x32_bf16(           \
                    aS[ks], bx, accS[nt], 0, 0, 0);                           \
            }                                                                 \
        }                                                                     \
        _Pragma("unroll")                                                     \
        for (int nt = 0; nt < 4; ++nt) {                                      \
            int trow = (CT) * 64 + nt * 16 + l15;                             \
            bf16x4 gv;                                                        \
            float gsum = 0.f;                                                 \
            _Pragma("unroll")                                                 \
            for (int r = 0; r < 4; ++r) {                                     \
                float ea = __expf(2.f * accT[nt][r]);                         \
                float eb = __expf(-accS[nt][r]);                              \
                float g  = (ea - 1.f) *                                       \
                           __builtin_amdgcn_rcpf((ea + 1.f) * (1.f + eb));    \
                gsum += mw4[r] * g;                                           \
                gv[r] = f2bf(g);                                              \
            }                                                                 \
            skp[((CT) - 1) * 4 + nt] += gsum;                                 \
            *(bf16x4*)(&G[SW(trow, m0 + quad * 4)]) = gv;                     \
        }                                                                     \
    } while (0)

// ---- GEMM2+epilogue, chunk 0, tiles nt = N0..3 (N0 literal) ----
#define G2_CHUNK0(N0)                                                         \
    do {                                                                      \
        f32x4 accR[4];                                                        \
        _Pragma("unroll")                                                     \
        for (int nt = N0; nt < 4; ++nt) accR[nt] = biasR;                     \
        _Pragma("unroll")                                                     \
        for (int ks = 0; ks < 2; ++ks) {                                      \
            const int koff = ks * 32 + quad * 8;                              \
            _Pragma("unroll")                                                 \
            for (int nt = N0; nt < 4; ++nt) {                                 \
                int trow = nt * 16 + l15;                                     \
                bf16x8 bx = *(const bf16x8*)(&G[SW(trow, koff)]);             \
                accR[nt] = __builtin_amdgcn_mfma_f32_16x16x32_bf16(           \
                    aR[ks], bx, accR[nt], 0, 0, 0);                           \
            }                                                                 \
        }                                                                     \
        _Pragma("unroll")                                                     \
        for (int nt = N0; nt < 4; ++nt) {                                     \
            int trow = nt * 16 + l15;                                         \
            bf16x4 old = *(const bf16x4*)(&A[SW(trow, m0 + quad * 4)]);       \
            bool ok = (tw + trow) >= 0;                                       \
            bf16x4 ov;                                                        \
            _Pragma("unroll")                                                 \
            for (int r = 0; r < 4; ++r) {                                     \
                float v = accR[nt][r] + bf2f(old[r]);                         \
                ov[r] = f2bf(ok ? v : 0.f);                                   \
            }                                                                 \
            *(bf16x4*)(&A[SW(trow, m0 + quad * 4)]) = ov;                     \
        }                                                                     \
    } while (0)

// ---- GEMM2+epilogue, full chunk CT in {1,2} (rows >= 64: no causal mask) ----
#define G2_CHUNK_FULL(CT)                                                     \
    do {                                                                      \
        f32x4 accR[4];                                                        \
        _Pragma("unroll")                                                     \
        for (int nt = 0; nt < 4; ++nt) accR[nt] = biasR;                      \
        _Pragma("unroll")                                                     \
        for (int ks = 0; ks < 2; ++ks) {                                      \
            const int koff = ks * 32 + quad * 8;                              \
            _Pragma("unroll")                                                 \
            for (int nt = 0; nt < 4; ++nt) {                                  \
                int trow = (CT) * 64 + nt * 16 + l15;                         \
                bf16x8 bx = *(const bf16x8*)(&G[SW(trow, koff)]);             \
                accR[nt] = __builtin_amdgcn_mfma_f32_16x16x32_bf16(           \
                    aR[ks], bx, accR[nt], 0, 0, 0);                           \
            }                                                                 \
        }                                                                     \
        _Pragma("unroll")                                                     \
        for (int nt = 0; nt < 4; ++nt) {                                      \
            int trow = (CT) * 64 + nt * 16 + l15;                             \
            bf16x4 old = *(const bf16x4*)(&A[SW(trow, m0 + quad * 4)]);       \
            bf16x4 ov;                                                        \
            _Pragma("unroll")                                                 \
            for (int r = 0; r < 4; ++r) {                                     \
                ov[r] = f2bf(accR[nt][r] + bf2f(old[r]));                     \
            }                                                                 \
            *(bf16x4*)(&A[SW(trow, m0 + quad * 4)]) = ov;                     \
        }                                                                     \
    } while (0)

#pragma unroll 1
    for (int l = 0; l < 6; ++l) {
        const int d = 1 << l;
        const __hip_bfloat16* whid = whid_all + (size_t)(lbase + l) * 16384;
        const __hip_bfloat16* wres = wres_all + (size_t)(lbase + l) * 4096;
        const float* hb = hb_all + (lbase + l) * 128;
        const float* rb = rb_all + (lbase + l) * 64;
        const float* mw = mix_w + (lbase + l) * 64;

        // ---- per-layer weights to registers ----
        bf16x8 aT[4], aS[4], aR[2];
        {
            const __hip_bfloat16* whT = whid + (size_t)(m0 + l15) * 128 + quad * 8;
            const __hip_bfloat16* whS = whT + 64 * 128;
#pragma unroll
            for (int k = 0; k < 4; ++k) {
                aT[k] = *(const bf16x8*)(whT + k * 32);
                aS[k] = *(const bf16x8*)(whS + k * 32);
            }
            const __hip_bfloat16* wrA = wres + (size_t)(m0 + l15) * 64 + quad * 8;
            aR[0] = *(const bf16x8*)(wrA);
            aR[1] = *(const bf16x8*)(wrA + 32);
        }
        f32x4 biasT, biasS, biasR;
#pragma unroll
        for (int r = 0; r < 4; ++r) {
            biasT[r] = hb[m0 + quad * 4 + r];
            biasS[r] = hb[64 + m0 + quad * 4 + r];
            biasR[r] = rb[m0 + quad * 4 + r];
        }
        // own-channel mix weights (4 floats, 16B-aligned)
        f32x4 mw4 = *(const f32x4*)(mw + m0 + quad * 4);

        __syncthreads();   // staging / previous epilogue A-writes visible

        // ---- phase 1: GEMM1 + gate ----
        // chunk 0: static variant by dilation (dead-halo tiles skipped)
        if (d < 8)        G1_CHUNK0(0);
        else if (d == 8)  G1_CHUNK0(1);
        else if (d == 16) G1_CHUNK0(2);
        /* d == 32: chunk 0 entirely below validity edge -> skip */
        G1_CHUNK_FULL(1);
        G1_CHUNK_FULL(2);
        __syncthreads();  // G complete, all A-reads of GEMM1 done

        // ---- phase 2: GEMM2 + in-place residual epilogue ----
        if (d < 8)        G2_CHUNK0(0);
        else if (d == 8)  G2_CHUNK0(1);
        else if (d == 16) G2_CHUNK0(2);
        /* d == 32: skip */
        G2_CHUNK_FULL(1);
        G2_CHUNK_FULL(2);
    }
    __syncthreads();  // last epilogue visible, last G reads done

    // ---- write output window [t0, t0+128) ----
#pragma unroll
    for (int round = 0; round < 4; ++round) {
        int pr = round * 32 + rr;
        *(bf16x8*)(next + ((size_t)b * T_LEN + t0 + pr) * NCH + co) =
            *(const bf16x8*)(&A[SW(pr + 64, co)]);
    }

    // ---- skip: quad-reduce in-wave, cross-wave via skbuf (overlays G) ----
    float* skbuf = (float*)G;   // [4][128] = 2 KB, G is dead now
#pragma unroll
    for (int i = 0; i < 8; ++i) {
        skp[i] += __shfl_xor(skp[i], 16, 64);
        skp[i] += __shfl_xor(skp[i], 32, 64);
    }
    if (quad == 0) {
#pragma unroll
        for (int i = 0; i < 8; ++i) {
            int ct = i >> 2, nt = i & 3;
            skbuf[w4 * 128 + ct * 64 + nt * 16 + l15] = skp[i];
        }
    }
    __syncthreads();
    if (tid < 128) {
        float tot = skbuf[tid] + skbuf[128 + tid] +
                    skbuf[256 + tid] + skbuf[384 + tid];
        acc[(size_t)b * T_LEN + t0 + tid] += tot;
    }
#undef SW
#undef G1_CHUNK0
#undef G1_CHUNK_FULL
#undef G2_CHUNK0
#undef G2_CHUNK_FULL
}

// ---------------------------------------------------------------------------
// Single-layer pass (R9 low-VGPR version -- kept: passed, tail declared
// dependency-bound/converged per R9 decision rule).
// ---------------------------------------------------------------------------
__global__ __launch_bounds__(256, 3) void layer_mfma_kernel(
    const __hip_bfloat16* __restrict__ prev,   // [B][T][C] bf16
    __hip_bfloat16* __restrict__ next,         // [B][T][C] bf16
    float* __restrict__ acc,                   // [B][T]
    const __hip_bfloat16* __restrict__ whid,   // [128][128] this layer
    const float* __restrict__ hb,              // [128]
    const __hip_bfloat16* __restrict__ wres,   // [64][64]
    const float* __restrict__ rb,              // [64]
    const float* __restrict__ mw,              // [64]
    int d) {
    __shared__ __align__(16) __hip_bfloat16 Xp[64 * 72];
    __shared__ __align__(16) __hip_bfloat16 Xc[64 * 72];
    __shared__ __align__(16) __hip_bfloat16 Gt[64 * 72];
    __shared__ float skb[4 * 64];   // 1 KB; total LDS 28.7 KB

    const int t0   = blockIdx.x << 6;
    const int tid  = threadIdx.x;
    const int lane = tid & 63;
    const int w4   = tid >> 6;
    const int l15  = lane & 15;
    const int quad = lane >> 4;
    const int m0   = w4 * 16;
    const int rr = tid >> 3;
    const int co = (tid & 7) * 8;

    bf16x8 aT[4], aS[4];
    {
        const __hip_bfloat16* whT = whid + (size_t)(m0 + l15) * 128 + quad * 8;
        const __hip_bfloat16* whS = whT + 64 * 128;
#pragma unroll
        for (int k = 0; k < 4; ++k) {
            aT[k] = *(const bf16x8*)(whT + k * 32);
            aS[k] = *(const bf16x8*)(whS + k * 32);
        }
    }
    f32x4 biasT, biasS;
#pragma unroll
    for (int r = 0; r < 4; ++r) {
        biasT[r] = hb[m0 + quad * 4 + r];
        biasS[r] = hb[64 + m0 + quad * 4 + r];
    }
    f32x4 mw4 = *(const f32x4*)(mw + m0 + quad * 4);

#pragma unroll 1
    for (int b = 0; b < 4; ++b) {
        // ---- stage (no prefetch; latency hidden by co-resident blocks) ----
        {
            const __hip_bfloat16* pb = prev + ((size_t)b * T_LEN + t0) * NCH;
#pragma unroll
            for (int pass = 0; pass < 2; ++pass) {
                int r = pass * 32 + rr;
                bf16x8 vc = *(const bf16x8*)(pb + r * NCH + co);
                int tp = t0 + r - d;
                bf16x8 vp = {0, 0, 0, 0, 0, 0, 0, 0};
                if (tp >= 0)
                    vp = *(const bf16x8*)(prev + ((size_t)b * T_LEN + tp) * NCH + co);
                *(bf16x8*)(&Xc[r * 72 + co]) = vc;
                *(bf16x8*)(&Xp[r * 72 + co]) = vp;
            }
        }
        __syncthreads();                       // barrier A

        // ---- GEMM1 + gate + in-register skip, in nt-pairs ----
        float sk[4];
#pragma unroll
        for (int np = 0; np < 2; ++np) {
            f32x4 accT[2], accS[2];
#pragma unroll
            for (int h = 0; h < 2; ++h) { accT[h] = biasT; accS[h] = biasS; }
#pragma unroll
            for (int ks = 0; ks < 4; ++ks) {
                const __hip_bfloat16* srcb = (ks < 2) ? Xp : Xc;
                const int kk = (ks & 1) * 32 + quad * 8;
#pragma unroll
                for (int h = 0; h < 2; ++h) {
                    int nt = np * 2 + h;
                    bf16x8 bx = *(const bf16x8*)(&srcb[(nt * 16 + l15) * 72 + kk]);
                    accT[h] = __builtin_amdgcn_mfma_f32_16x16x32_bf16(aT[ks], bx, accT[h], 0, 0, 0);
                    accS[h] = __builtin_amdgcn_mfma_f32_16x16x32_bf16(aS[ks], bx, accS[h], 0, 0, 0);
                }
            }
#pragma unroll
            for (int h = 0; h < 2; ++h) {
                int nt = np * 2 + h;
                float gsum = 0.f;
#pragma unroll
                for (int r = 0; r < 4; ++r) {
                    float ea = __expf(2.f * accT[h][r]);
                    float eb = __expf(-accS[h][r]);
                    float g  = (ea - 1.f) *
                               __builtin_amdgcn_rcpf((ea + 1.f) * (1.f + eb));
                    gsum += mw4[r] * g;
                    Gt[(nt * 16 + l15) * 72 + m0 + quad * 4 + r] = __float2bfloat16(g);
                }
                sk[nt] = gsum;
            }
        }
        // skip: reduce over quad (16 channels), write per-wave partial
#pragma unroll
        for (int nt = 0; nt < 4; ++nt) {
            sk[nt] += __shfl_xor(sk[nt], 16, 64);
            sk[nt] += __shfl_xor(sk[nt], 32, 64);
        }
        if (quad == 0) {
#pragma unroll
            for (int nt = 0; nt < 4; ++nt)
                skb[w4 * 64 + nt * 16 + l15] = sk[nt];
        }

        bf16x4 curres[4];
#pragma unroll
        for (int nt = 0; nt < 4; ++nt) {
            curres[nt] = *(const bf16x4*)(&Xc[(nt * 16 + l15) * 72 + m0 + quad * 4]);
        }
        __syncthreads();                       // barrier B (Gt + skb visible)

        // ---- deferred res-conv weights (L2-hot reload per batch) ----
        bf16x8 aR0, aR1;
        {
            const __hip_bfloat16* wrA = wres + (size_t)(m0 + l15) * 64 + quad * 8;
            aR0 = *(const bf16x8*)(wrA);
            aR1 = *(const bf16x8*)(wrA + 32);
        }
        f32x4 biasR;
#pragma unroll
        for (int r = 0; r < 4; ++r) biasR[r] = rb[m0 + quad * 4 + r];

        f32x4 accR[4];
#pragma unroll
        for (int nt = 0; nt < 4; ++nt) accR[nt] = biasR;
#pragma unroll
        for (int ks = 0; ks < 2; ++ks) {
            const int kk = ks * 32 + quad * 8;
#pragma unroll
            for (int nt = 0; nt < 4; ++nt) {
                bf16x8 bx = *(const bf16x8*)(&Gt[(nt * 16 + l15) * 72 + kk]);
                accR[nt] = __builtin_amdgcn_mfma_f32_16x16x32_bf16(
                    (ks == 0) ? aR0 : aR1, bx, accR[nt], 0, 0, 0);
            }
        }

        __hip_bfloat16* nb = next + ((size_t)b * T_LEN + t0) * NCH;
#pragma unroll
        for (int nt = 0; nt < 4; ++nt) {
            int t = nt * 16 + l15;
            bf16x4 ov;
#pragma unroll
            for (int r = 0; r < 4; ++r) {
                ov[r] = f2bf(accR[nt][r] + bf2f(curres[nt][r]));
            }
            *(bf16x4*)(nb + t * NCH + m0 + quad * 4) = ov;
        }

        // ---- skip finalize: sum 4 wave-partials, one RMW per t ----
        if (tid < 64) {
            float tot = skb[tid] + skb[64 + tid] + skb[128 + tid] + skb[192 + tid];
            acc[(size_t)b * T_LEN + t0 + tid] += tot;
        }
        // next iteration's skb writes are after barrier A(b+1) -> no race
    }
}

// ---------------------------------------------------------------------------
// Last layer (17, d=256): GEMM1 + gate + skip only (res-conv output unused),
// fused finalize: out = acc + own skip + mix_b. No next write. (R2 config.)
// ---------------------------------------------------------------------------
__global__ __launch_bounds__(256, 2) void last_layer_kernel(
    const __hip_bfloat16* __restrict__ prev,   // [B][T][C]
    const float* __restrict__ acc,             // [B][T] (layers 0..16 summed)
    float* __restrict__ out,                   // [B][T] fp32
    const __hip_bfloat16* __restrict__ whid,   // [128][128] layer 17
    const float* __restrict__ hb,              // [128]
    const float* __restrict__ mw,              // [64] layer-17 mix slice
    const float* __restrict__ mix_b,           // [1]
    int d) {
    __shared__ __align__(16) __hip_bfloat16 Xp[64 * 72];
    __shared__ __align__(16) __hip_bfloat16 Xc[64 * 72];
    __shared__ float skb[4 * 64];

    const int t0   = blockIdx.x << 6;
    const int tid  = threadIdx.x;
    const int lane = tid & 63;
    const int w4   = tid >> 6;
    const int l15  = lane & 15;
    const int quad = lane >> 4;
    const int m0   = w4 * 16;
    const int rr = tid >> 3;
    const int co = (tid & 7) * 8;

    bf16x8 aT[4], aS[4];
    {
        const __hip_bfloat16* whT = whid + (size_t)(m0 + l15) * 128 + quad * 8;
        const __hip_bfloat16* whS = whT + 64 * 128;
#pragma unroll
        for (int k = 0; k < 4; ++k) {
            aT[k] = *(const bf16x8*)(whT + k * 32);
            aS[k] = *(const bf16x8*)(whS + k * 32);
        }
    }
    f32x4 biasT, biasS;
    float mwv[4];
#pragma unroll
    for (int r = 0; r < 4; ++r) {
        biasT[r] = hb[m0 + quad * 4 + r];
        biasS[r] = hb[64 + m0 + quad * 4 + r];
        mwv[r]   = mw[m0 + quad * 4 + r];
    }
    const float mb = mix_b[0];

    bf16x8 pc[2], pp[2];
#define LOAD_TILE(b)                                                          \
    do {                                                                      \
        const __hip_bfloat16* pb = prev + ((size_t)(b) * T_LEN + t0) * NCH;   \
        _Pragma("unroll")                                                     \
        for (int pass = 0; pass < 2; ++pass) {                                \
            int r = pass * 32 + rr;                                           \
            pc[pass] = *(const bf16x8*)(pb + r * NCH + co);                   \
            int tp = t0 + r - d;                                              \
            bf16x8 z = {0, 0, 0, 0, 0, 0, 0, 0};                              \
            pp[pass] = z;                                                     \
            if (tp >= 0)                                                      \
                pp[pass] = *(const bf16x8*)(prev +                            \
                    ((size_t)(b) * T_LEN + tp) * NCH + co);                   \
        }                                                                     \
    } while (0)

    LOAD_TILE(0);

#pragma unroll
    for (int b = 0; b < 4; ++b) {
#pragma unroll
        for (int pass = 0; pass < 2; ++pass) {
            int r = pass * 32 + rr;
            *(bf16x8*)(&Xc[r * 72 + co]) = pc[pass];
            *(bf16x8*)(&Xp[r * 72 + co]) = pp[pass];
        }
        __syncthreads();                       // barrier A

        if (b < 3) LOAD_TILE(b + 1);

        f32x4 accT[4], accS[4];
#pragma unroll
        for (int nt = 0; nt < 4; ++nt) { accT[nt] = biasT; accS[nt] = biasS; }
#pragma unroll
        for (int ks = 0; ks < 4; ++ks) {
            const __hip_bfloat16* srcb = (ks < 2) ? Xp : Xc;
            const int kk = (ks & 1) * 32 + quad * 8;
#pragma unroll
            for (int nt = 0; nt < 4; ++nt) {
                bf16x8 bx = *(const bf16x8*)(&srcb[(nt * 16 + l15) * 72 + kk]);
                accT[nt] = __builtin_amdgcn_mfma_f32_16x16x32_bf16(aT[ks], bx, accT[nt], 0, 0, 0);
                accS[nt] = __builtin_amdgcn_mfma_f32_16x16x32_bf16(aS[ks], bx, accS[nt], 0, 0, 0);
            }
        }

        // gate + skip partial (no Gt/GEMM2 needed for last layer)
#pragma unroll
        for (int nt = 0; nt < 4; ++nt) {
            float sv = 0.f;
#pragma unroll
            for (int r = 0; r < 4; ++r) {
                float e2 = __expf(2.f * accT[nt][r]);
                float th = 1.f - 2.f * __builtin_amdgcn_rcpf(e2 + 1.f);
                float sg = __builtin_amdgcn_rcpf(1.f + __expf(-accS[nt][r]));
                sv += mwv[r] * (th * sg);
            }
            sv += __shfl_xor(sv, 16, 64);
            sv += __shfl_xor(sv, 32, 64);
            if (quad == 0)
                skb[w4 * 64 + nt * 16 + l15] = sv;
        }
        __syncthreads();                       // barrier B

        if (tid < 64) {
            float tot = skb[tid] + skb[64 + tid] + skb[128 + tid] + skb[192 + tid];
            out[(size_t)b * T_LEN + t0 + tid] =
                acc[(size_t)b * T_LEN + t0 + tid] + tot + mb;
        }
    }
#undef LOAD_TILE
}

// ---------------------------------------------------------------------------
extern "C" void kernel_launch(void* const* d_in, const int* in_sizes, int n_in,
                              void* d_out, int out_size, void* d_ws, size_t ws_size,
                              hipStream_t stream) {
    const float* x     = (const float*)d_in[0];
    const float* in_w  = (const float*)d_in[1];
    const float* in_b  = (const float*)d_in[2];
    const float* hid_w = (const float*)d_in[3];  // [18][128][64][2]
    const float* hid_b = (const float*)d_in[4];  // [18][128]
    const float* res_w = (const float*)d_in[5];  // [18][64][64][1]
    const float* res_b = (const float*)d_in[6];  // [18][64]
    const float* mix_w = (const float*)d_in[7];  // [1152]
    const float* mix_b = (const float*)d_in[8];  // [1]
    float* out = (float*)d_out;

    // ws layout: actA 32M | actB 32M | acc 1M | whid 0.56M | wres 0.14M
    const size_t act_elems = 4ull * T_LEN * NCH;     // 16M bf16 = 32 MB
    __hip_bfloat16* actA = (__hip_bfloat16*)d_ws;
    __hip_bfloat16* actB = actA + act_elems;
    float* acc = (float*)(actB + act_elems);         // [B][T] = 1 MB
    __hip_bfloat16* whid = (__hip_bfloat16*)(acc + 4ull * T_LEN);
    __hip_bfloat16* wres = whid + (size_t)NLAYER * 128 * 128;

    hipMemsetAsync(acc, 0, 4ull * T_LEN * sizeof(float), stream);

    convert_weights_kernel<<<1152, 256, 0, stream>>>(hid_w, res_w, whid, wres);

    // P0: input conv + layers 0-5 (d=1..32) fused -> actA
    fused6_kernel<<<2048, 256, 0, stream>>>(
        x, actA, acc, whid, hid_b, wres, res_b, mix_w, in_w, in_b, 0, 1);

    // P1-P3: layers 6,7,8 (d=64,128,256)
    layer_mfma_kernel<<<1024, 256, 0, stream>>>(
        actA, actB, acc, whid + 6 * 16384, hid_b + 6 * 128,
        wres + 6 * 4096, res_b + 6 * 64, mix_w + 6 * 64, 64);
    layer_mfma_kernel<<<1024, 256, 0, stream>>>(
        actB, actA, acc, whid + 7 * 16384, hid_b + 7 * 128,
        wres + 7 * 4096, res_b + 7 * 64, mix_w + 7 * 64, 128);
    layer_mfma_kernel<<<1024, 256, 0, stream>>>(
        actA, actB, acc, whid + 8 * 16384, hid_b + 8 * 128,
        wres + 8 * 4096, res_b + 8 * 64, mix_w + 8 * 64, 256);

    // P4: layers 9-14 (d=1..32) fused -> actA
    fused6_kernel<<<2048, 256, 0, stream>>>(
        actB, actA, acc, whid, hid_b, wres, res_b, mix_w, in_w, in_b, 9, 0);

    // P5-P6: layers 15,16 (d=64,128)
    layer_mfma_kernel<<<1024, 256, 0, stream>>>(
        actA, actB, acc, whid + 15 * 16384, hid_b + 15 * 128,
        wres + 15 * 4096, res_b + 15 * 64, mix_w + 15 * 64, 64);
    layer_mfma_kernel<<<1024, 256, 0, stream>>>(
        actB, actA, acc, whid + 16 * 16384, hid_b + 16 * 128,
        wres + 16 * 4096, res_b + 16 * 64, mix_w + 16 * 64, 128);

    // P7: layer 17 (d=256) + finalize -> out
    last_layer_kernel<<<1024, 256, 0, stream>>>(
        actA, acc, out, whid + 17 * 16384, hid_b + 17 * 128,
        mix_w + 17 * 64, mix_b, 256);
}

// Round 13
// 485.693 us; speedup vs baseline: 2.1801x; 1.0076x over previous
//
#include <hip/hip_runtime.h>
#include <hip/hip_bf16.h>
#include <math.h>

#define NCH 64       // C
#define T_LEN 65536
#define NLAYER 18

typedef __attribute__((ext_vector_type(8))) short bf16x8;   // 8 bf16 = 4 VGPRs
typedef __attribute__((ext_vector_type(4))) short bf16x4;   // 4 bf16 = 2 VGPRs
typedef __attribute__((ext_vector_type(4))) float f32x4;

static __device__ __forceinline__ float bf2f(short s) {
    union { short u[2]; float f; } v;
    v.u[0] = 0; v.u[1] = s;
    return v.f;
}
static __device__ __forceinline__ short f2bf(float f) {
    __hip_bfloat16 h = __float2bfloat16(f);
    return *(short*)&h;
}

// ---------------------------------------------------------------------------
// whid[l][o][k]: k<64 -> hid_w[l][o][k][0] (past tap), k>=64 -> [k-64][1] (cur)
// ---------------------------------------------------------------------------
__global__ void convert_weights_kernel(const float* __restrict__ hid_w,
                                       const float* __restrict__ res_w,
                                       __hip_bfloat16* __restrict__ whid,
                                       __hip_bfloat16* __restrict__ wres) {
    int gid = blockIdx.x * 256 + threadIdx.x;
    if (gid < NLAYER * 128 * 128) {
        int l   = gid >> 14;
        int rem = gid & 16383;
        int o   = rem >> 7;
        int k   = rem & 127;
        float v = (k < 64)
            ? hid_w[((l * 128 + o) * 64 + k) * 2]
            : hid_w[((l * 128 + o) * 64 + (k - 64)) * 2 + 1];
        whid[gid] = __float2bfloat16(v);
    }
    if (gid < NLAYER * 64 * 64) {
        wres[gid] = __float2bfloat16(res_w[gid]);
    }
}

// ---------------------------------------------------------------------------
// Fused 6-layer pass -- R11 structure (dead-halo static-variant skip) +
// ROUND-12: (a) __launch_bounds__(256,2): VGPR budget 128 instead of 85.
// R11's VGPR sat at 84 = cap-1 (binding). Residency is LDS-capped at
// 3 blocks/CU (48KB) independent of VGPR up to 170 regs (3x170 <= 512/SIMD),
// so the bigger budget is pure scheduling headroom, zero occupancy risk.
// (b) s_setprio(1) around MFMA clusters: 3 independent blocks/CU drift out
// of phase (one block's gate-VALU overlaps another's MFMA -- the measured
// 25+52=77% combined); priority biases arbitration toward the MFMA-starved
// pipe (T5 positive regime = independent blocks, unlike lockstep m190).
//
// Validity edge: after layer l (d=2^l) only rows >= E_l = 2^(l+1) are
// consumed downstream. Chunk-0 tiles below the edge skipped via THREE
// compile-time variants (N0 = 0/1/2 literal; d=32 skips chunk 0 entirely).
// R10 lesson: runtime guards in unrolled MFMA loops -> conditional liveness
// -> spill. Static variants only.
//
// LDS: A/G [192][64] bf16, XOR swizzle col ^= (row&7)<<3 (bank-minimal).
// Gate: tanh(x)*sigmoid(y) = (e^2x-1)/((e^2x+1)(1+e^-y)) -- one rcp.
// Skip->mix in registers, one reduce at kernel end via shfl + skbuf over G.
// ---------------------------------------------------------------------------
__global__ __launch_bounds__(256, 2) void fused6_kernel(
    const void* __restrict__ src,                 // fp32 x | bf16 prev
    __hip_bfloat16* __restrict__ next,            // [B][T][C]
    float* __restrict__ acc,                      // [B][T]
    const __hip_bfloat16* __restrict__ whid_all,  // [18][128][128]
    const float* __restrict__ hb_all,             // [18][128]
    const __hip_bfloat16* __restrict__ wres_all,  // [18][64][64]
    const float* __restrict__ rb_all,             // [18][64]
    const float* __restrict__ mix_w,              // [1152]
    const float* __restrict__ in_w,               // [64]
    const float* __restrict__ in_b,               // [64]
    int lbase, int is_first) {
    __shared__ __align__(16) __hip_bfloat16 A[192 * 64];
    __shared__ __align__(16) __hip_bfloat16 G[192 * 64];

#define SW(row, col) ((row) * 64 + ((col) ^ (((row) & 7) << 3)))

    const int b    = blockIdx.x >> 9;          // 512 windows per batch
    const int widx = blockIdx.x & 511;
    const int t0   = widx << 7;
    const int tw   = t0 - 64;

    const int tid  = threadIdx.x;
    const int lane = tid & 63;
    const int w4   = tid >> 6;
    const int l15  = lane & 15;
    const int quad = lane >> 4;
    const int m0   = w4 * 16;
    const int rr   = tid >> 3;                 // 0..31
    const int co   = (tid & 7) * 8;

    // ---- stage input window [tw, tw+192) ----
    if (is_first) {
        const float* x = (const float*)src;
        float iw[8], ib[8];
#pragma unroll
        for (int j = 0; j < 8; ++j) { iw[j] = in_w[co + j]; ib[j] = in_b[co + j]; }
#pragma unroll
        for (int round = 0; round < 6; ++round) {
            int r  = round * 32 + rr;
            int gt = tw + r;
            bf16x8 v = {0, 0, 0, 0, 0, 0, 0, 0};
            if (gt >= 0) {
                float xv = x[(size_t)b * T_LEN + gt];
#pragma unroll
                for (int j = 0; j < 8; ++j) v[j] = f2bf(iw[j] * xv + ib[j]);
            }
            *(bf16x8*)(&A[SW(r, co)]) = v;
        }
    } else {
        const __hip_bfloat16* prev = (const __hip_bfloat16*)src;
#pragma unroll
        for (int round = 0; round < 6; ++round) {
            int r  = round * 32 + rr;
            int gt = tw + r;
            bf16x8 v = {0, 0, 0, 0, 0, 0, 0, 0};
            if (gt >= 0)
                v = *(const bf16x8*)(prev + ((size_t)b * T_LEN + gt) * NCH + co);
            *(bf16x8*)(&A[SW(r, co)]) = v;
        }
    }

    // per-thread skip partials for the 8 owned output rows
    // index (ct-1)*4 + nt  ->  row = ct*64 + nt*16 + l15, ct in {1,2}
    float skp[8] = {0.f, 0.f, 0.f, 0.f, 0.f, 0.f, 0.f, 0.f};

// ---- GEMM1+gate, chunk 0, tiles nt = N0..3 (N0 is a macro LITERAL) ----
#define G1_CHUNK0(N0)                                                         \
    do {                                                                      \
        f32x4 accT[4], accS[4];                                               \
        _Pragma("unroll")                                                     \
        for (int nt = N0; nt < 4; ++nt) { accT[nt] = biasT; accS[nt] = biasS; } \
        __builtin_amdgcn_s_setprio(1);                                        \
        _Pragma("unroll")                                                     \
        for (int ks = 0; ks < 4; ++ks) {                                      \
            const int koff = (ks & 1) * 32 + quad * 8;                        \
            _Pragma("unroll")                                                 \
            for (int nt = N0; nt < 4; ++nt) {                                 \
                int trow = nt * 16 + l15;                                     \
                int prow = trow - d;  prow = prow < 0 ? 0 : prow;             \
                int row  = (ks < 2) ? prow : trow;                            \
                bf16x8 bx = *(const bf16x8*)(&A[SW(row, koff)]);              \
                accT[nt] = __builtin_amdgcn_mfma_f32_16x16x32_bf16(           \
                    aT[ks], bx, accT[nt], 0, 0, 0);                           \
                accS[nt] = __builtin_amdgcn_mfma_f32_16x16x32_bf16(           \
                    aS[ks], bx, accS[nt], 0, 0, 0);                           \
            }                                                                 \
        }                                                                     \
        __builtin_amdgcn_s_setprio(0);                                        \
        _Pragma("unroll")                                                     \
        for (int nt = N0; nt < 4; ++nt) {                                     \
            int trow = nt * 16 + l15;                                         \
            bf16x4 gv;                                                        \
            _Pragma("unroll")                                                 \
            for (int r = 0; r < 4; ++r) {                                     \
                float ea = __expf(2.f * accT[nt][r]);                         \
                float eb = __expf(-accS[nt][r]);                              \
                float g  = (ea - 1.f) *                                       \
                           __builtin_amdgcn_rcpf((ea + 1.f) * (1.f + eb));    \
                gv[r] = f2bf(g);                                              \
            }                                                                 \
            *(bf16x4*)(&G[SW(trow, m0 + quad * 4)]) = gv;                     \
        }                                                                     \
    } while (0)

// ---- GEMM1+gate+skip, full chunk CT in {1,2} ----
#define G1_CHUNK_FULL(CT)                                                     \
    do {                                                                      \
        f32x4 accT[4], accS[4];                                               \
        _Pragma("unroll")                                                     \
        for (int nt = 0; nt < 4; ++nt) { accT[nt] = biasT; accS[nt] = biasS; } \
        __builtin_amdgcn_s_setprio(1);                                        \
        _Pragma("unroll")                                                     \
        for (int ks = 0; ks < 4; ++ks) {                                      \
            const int koff = (ks & 1) * 32 + quad * 8;                        \
            _Pragma("unroll")                                                 \
            for (int nt = 0; nt < 4; ++nt) {                                  \
                int trow = (CT) * 64 + nt * 16 + l15;                         \
                int row  = (ks < 2) ? (trow - d) : trow;                      \
                bf16x8 bx = *(const bf16x8*)(&A[SW(row, koff)]);              \
                accT[nt] = __builtin_amdgcn_mfma_f32_16x16x32_bf16(           \
                    aT[ks], bx, accT[nt], 0, 0, 0);                           \
                accS[nt] = __builtin_amdgcn_mfma_f32_16x16x32_bf16(           \
                    aS[ks], bx, accS[nt], 0, 0, 0);                           \
            }                                                                 \
        }                                                                     \
        __builtin_amdgcn_s_setprio(0);                                        \
        _Pragma("unroll")                                                     \
        for (int nt = 0; nt < 4; ++nt) {                                      \
            int trow = (CT) * 64 + nt * 16 + l15;                             \
            bf16x4 gv;                                                        \
            float gsum = 0.f;                                                 \
            _Pragma("unroll")                                                 \
            for (int r = 0; r < 4; ++r) {                                     \
                float ea = __expf(2.f * accT[nt][r]);                         \
                float eb = __expf(-accS[nt][r]);                              \
                float g  = (ea - 1.f) *                                       \
                           __builtin_amdgcn_rcpf((ea + 1.f) * (1.f + eb));    \
                gsum += mw4[r] * g;                                           \
                gv[r] = f2bf(g);                                              \
            }                                                                 \
            skp[((CT) - 1) * 4 + nt] += gsum;                                 \
            *(bf16x4*)(&G[SW(trow, m0 + quad * 4)]) = gv;                     \
        }                                                                     \
    } while (0)

// ---- GEMM2+epilogue, chunk 0, tiles nt = N0..3 (N0 literal) ----
#define G2_CHUNK0(N0)                                                         \
    do {                                                                      \
        f32x4 accR[4];                                                        \
        _Pragma("unroll")                                                     \
        for (int nt = N0; nt < 4; ++nt) accR[nt] = biasR;                     \
        __builtin_amdgcn_s_setprio(1);                                        \
        _Pragma("unroll")                                                     \
        for (int ks = 0; ks < 2; ++ks) {                                      \
            const int koff = ks * 32 + quad * 8;                              \
            _Pragma("unroll")                                                 \
            for (int nt = N0; nt < 4; ++nt) {                                 \
                int trow = nt * 16 + l15;                                     \
                bf16x8 bx = *(const bf16x8*)(&G[SW(trow, koff)]);             \
                accR[nt] = __builtin_amdgcn_mfma_f32_16x16x32_bf16(           \
                    aR[ks], bx, accR[nt], 0, 0, 0);                           \
            }                                                                 \
        }                                                                     \
        __builtin_amdgcn_s_setprio(0);                                        \
        _Pragma("unroll")                                                     \
        for (int nt = N0; nt < 4; ++nt) {                                     \
            int trow = nt * 16 + l15;                                         \
            bf16x4 old = *(const bf16x4*)(&A[SW(trow, m0 + quad * 4)]);       \
            bool ok = (tw + trow) >= 0;                                       \
            bf16x4 ov;                                                        \
            _Pragma("unroll")                                                 \
            for (int r = 0; r < 4; ++r) {                                     \
                float v = accR[nt][r] + bf2f(old[r]);                         \
                ov[r] = f2bf(ok ? v : 0.f);                                   \
            }                                                                 \
            *(bf16x4*)(&A[SW(trow, m0 + quad * 4)]) = ov;                     \
        }                                                                     \
    } while (0)

// ---- GEMM2+epilogue, full chunk CT in {1,2} (rows >= 64: no causal mask) ----
#define G2_CHUNK_FULL(CT)                                                     \
    do {                                                                      \
        f32x4 accR[4];                                                        \
        _Pragma("unroll")                                                     \
        for (int nt = 0; nt < 4; ++nt) accR[nt] = biasR;                      \
        __builtin_amdgcn_s_setprio(1);                                        \
        _Pragma("unroll")                                                     \
        for (int ks = 0; ks < 2; ++ks) {                                      \
            const int koff = ks * 32 + quad * 8;                              \
            _Pragma("unroll")                                                 \
            for (int nt = 0; nt < 4; ++nt) {                                  \
                int trow = (CT) * 64 + nt * 16 + l15;                         \
                bf16x8 bx = *(const bf16x8*)(&G[SW(trow, koff)]);             \
                accR[nt] = __builtin_amdgcn_mfma_f32_16x16x32_bf16(           \
                    aR[ks], bx, accR[nt], 0, 0, 0);                           \
            }                                                                 \
        }                                                                     \
        __builtin_amdgcn_s_setprio(0);                                        \
        _Pragma("unroll")                                                     \
        for (int nt = 0; nt < 4; ++nt) {                                      \
            int trow = (CT) * 64 + nt * 16 + l15;                             \
            bf16x4 old = *(const bf16x4*)(&A[SW(trow, m0 + quad * 4)]);       \
            bf16x4 ov;                                                        \
            _Pragma("unroll")                                                 \
            for (int r = 0; r < 4; ++r) {                                     \
                ov[r] = f2bf(accR[nt][r] + bf2f(old[r]));                     \
            }                                                                 \
            *(bf16x4*)(&A[SW(trow, m0 + quad * 4)]) = ov;                     \
        }                                                                     \
    } while (0)

#pragma unroll 1
    for (int l = 0; l < 6; ++l) {
        const int d = 1 << l;
        const __hip_bfloat16* whid = whid_all + (size_t)(lbase + l) * 16384;
        const __hip_bfloat16* wres = wres_all + (size_t)(lbase + l) * 4096;
        const float* hb = hb_all + (lbase + l) * 128;
        const float* rb = rb_all + (lbase + l) * 64;
        const float* mw = mix_w + (lbase + l) * 64;

        // ---- per-layer weights to registers ----
        bf16x8 aT[4], aS[4], aR[2];
        {
            const __hip_bfloat16* whT = whid + (size_t)(m0 + l15) * 128 + quad * 8;
            const __hip_bfloat16* whS = whT + 64 * 128;
#pragma unroll
            for (int k = 0; k < 4; ++k) {
                aT[k] = *(const bf16x8*)(whT + k * 32);
                aS[k] = *(const bf16x8*)(whS + k * 32);
            }
            const __hip_bfloat16* wrA = wres + (size_t)(m0 + l15) * 64 + quad * 8;
            aR[0] = *(const bf16x8*)(wrA);
            aR[1] = *(const bf16x8*)(wrA + 32);
        }
        f32x4 biasT, biasS, biasR;
#pragma unroll
        for (int r = 0; r < 4; ++r) {
            biasT[r] = hb[m0 + quad * 4 + r];
            biasS[r] = hb[64 + m0 + quad * 4 + r];
            biasR[r] = rb[m0 + quad * 4 + r];
        }
        // own-channel mix weights (4 floats, 16B-aligned)
        f32x4 mw4 = *(const f32x4*)(mw + m0 + quad * 4);

        __syncthreads();   // staging / previous epilogue A-writes visible

        // ---- phase 1: GEMM1 + gate ----
        // chunk 0: static variant by dilation (dead-halo tiles skipped)
        if (d < 8)        G1_CHUNK0(0);
        else if (d == 8)  G1_CHUNK0(1);
        else if (d == 16) G1_CHUNK0(2);
        /* d == 32: chunk 0 entirely below validity edge -> skip */
        G1_CHUNK_FULL(1);
        G1_CHUNK_FULL(2);
        __syncthreads();  // G complete, all A-reads of GEMM1 done

        // ---- phase 2: GEMM2 + in-place residual epilogue ----
        if (d < 8)        G2_CHUNK0(0);
        else if (d == 8)  G2_CHUNK0(1);
        else if (d == 16) G2_CHUNK0(2);
        /* d == 32: skip */
        G2_CHUNK_FULL(1);
        G2_CHUNK_FULL(2);
    }
    __syncthreads();  // last epilogue visible, last G reads done

    // ---- write output window [t0, t0+128) ----
#pragma unroll
    for (int round = 0; round < 4; ++round) {
        int pr = round * 32 + rr;
        *(bf16x8*)(next + ((size_t)b * T_LEN + t0 + pr) * NCH + co) =
            *(const bf16x8*)(&A[SW(pr + 64, co)]);
    }

    // ---- skip: quad-reduce in-wave, cross-wave via skbuf (overlays G) ----
    float* skbuf = (float*)G;   // [4][128] = 2 KB, G is dead now
#pragma unroll
    for (int i = 0; i < 8; ++i) {
        skp[i] += __shfl_xor(skp[i], 16, 64);
        skp[i] += __shfl_xor(skp[i], 32, 64);
    }
    if (quad == 0) {
#pragma unroll
        for (int i = 0; i < 8; ++i) {
            int ct = i >> 2, nt = i & 3;
            skbuf[w4 * 128 + ct * 64 + nt * 16 + l15] = skp[i];
        }
    }
    __syncthreads();
    if (tid < 128) {
        float tot = skbuf[tid] + skbuf[128 + tid] +
                    skbuf[256 + tid] + skbuf[384 + tid];
        acc[(size_t)b * T_LEN + t0 + tid] += tot;
    }
#undef SW
#undef G1_CHUNK0
#undef G1_CHUNK_FULL
#undef G2_CHUNK0
#undef G2_CHUNK_FULL
}

// ---------------------------------------------------------------------------
// Single-layer pass (R9 low-VGPR version -- kept unchanged as control;
// tail declared dependency-bound/converged per R9 decision rule).
// ---------------------------------------------------------------------------
__global__ __launch_bounds__(256, 3) void layer_mfma_kernel(
    const __hip_bfloat16* __restrict__ prev,   // [B][T][C] bf16
    __hip_bfloat16* __restrict__ next,         // [B][T][C] bf16
    float* __restrict__ acc,                   // [B][T]
    const __hip_bfloat16* __restrict__ whid,   // [128][128] this layer
    const float* __restrict__ hb,              // [128]
    const __hip_bfloat16* __restrict__ wres,   // [64][64]
    const float* __restrict__ rb,              // [64]
    const float* __restrict__ mw,              // [64]
    int d) {
    __shared__ __align__(16) __hip_bfloat16 Xp[64 * 72];
    __shared__ __align__(16) __hip_bfloat16 Xc[64 * 72];
    __shared__ __align__(16) __hip_bfloat16 Gt[64 * 72];
    __shared__ float skb[4 * 64];   // 1 KB; total LDS 28.7 KB

    const int t0   = blockIdx.x << 6;
    const int tid  = threadIdx.x;
    const int lane = tid & 63;
    const int w4   = tid >> 6;
    const int l15  = lane & 15;
    const int quad = lane >> 4;
    const int m0   = w4 * 16;
    const int rr = tid >> 3;
    const int co = (tid & 7) * 8;

    bf16x8 aT[4], aS[4];
    {
        const __hip_bfloat16* whT = whid + (size_t)(m0 + l15) * 128 + quad * 8;
        const __hip_bfloat16* whS = whT + 64 * 128;
#pragma unroll
        for (int k = 0; k < 4; ++k) {
            aT[k] = *(const bf16x8*)(whT + k * 32);
            aS[k] = *(const bf16x8*)(whS + k * 32);
        }
    }
    f32x4 biasT, biasS;
#pragma unroll
    for (int r = 0; r < 4; ++r) {
        biasT[r] = hb[m0 + quad * 4 + r];
        biasS[r] = hb[64 + m0 + quad * 4 + r];
    }
    f32x4 mw4 = *(const f32x4*)(mw + m0 + quad * 4);

#pragma unroll 1
    for (int b = 0; b < 4; ++b) {
        // ---- stage (no prefetch; latency hidden by co-resident blocks) ----
        {
            const __hip_bfloat16* pb = prev + ((size_t)b * T_LEN + t0) * NCH;
#pragma unroll
            for (int pass = 0; pass < 2; ++pass) {
                int r = pass * 32 + rr;
                bf16x8 vc = *(const bf16x8*)(pb + r * NCH + co);
                int tp = t0 + r - d;
                bf16x8 vp = {0, 0, 0, 0, 0, 0, 0, 0};
                if (tp >= 0)
                    vp = *(const bf16x8*)(prev + ((size_t)b * T_LEN + tp) * NCH + co);
                *(bf16x8*)(&Xc[r * 72 + co]) = vc;
                *(bf16x8*)(&Xp[r * 72 + co]) = vp;
            }
        }
        __syncthreads();                       // barrier A

        // ---- GEMM1 + gate + in-register skip, in nt-pairs ----
        float sk[4];
#pragma unroll
        for (int np = 0; np < 2; ++np) {
            f32x4 accT[2], accS[2];
#pragma unroll
            for (int h = 0; h < 2; ++h) { accT[h] = biasT; accS[h] = biasS; }
#pragma unroll
            for (int ks = 0; ks < 4; ++ks) {
                const __hip_bfloat16* srcb = (ks < 2) ? Xp : Xc;
                const int kk = (ks & 1) * 32 + quad * 8;
#pragma unroll
                for (int h = 0; h < 2; ++h) {
                    int nt = np * 2 + h;
                    bf16x8 bx = *(const bf16x8*)(&srcb[(nt * 16 + l15) * 72 + kk]);
                    accT[h] = __builtin_amdgcn_mfma_f32_16x16x32_bf16(aT[ks], bx, accT[h], 0, 0, 0);
                    accS[h] = __builtin_amdgcn_mfma_f32_16x16x32_bf16(aS[ks], bx, accS[h], 0, 0, 0);
                }
            }
#pragma unroll
            for (int h = 0; h < 2; ++h) {
                int nt = np * 2 + h;
                float gsum = 0.f;
#pragma unroll
                for (int r = 0; r < 4; ++r) {
                    float ea = __expf(2.f * accT[h][r]);
                    float eb = __expf(-accS[h][r]);
                    float g  = (ea - 1.f) *
                               __builtin_amdgcn_rcpf((ea + 1.f) * (1.f + eb));
                    gsum += mw4[r] * g;
                    Gt[(nt * 16 + l15) * 72 + m0 + quad * 4 + r] = __float2bfloat16(g);
                }
                sk[nt] = gsum;
            }
        }
        // skip: reduce over quad (16 channels), write per-wave partial
#pragma unroll
        for (int nt = 0; nt < 4; ++nt) {
            sk[nt] += __shfl_xor(sk[nt], 16, 64);
            sk[nt] += __shfl_xor(sk[nt], 32, 64);
        }
        if (quad == 0) {
#pragma unroll
            for (int nt = 0; nt < 4; ++nt)
                skb[w4 * 64 + nt * 16 + l15] = sk[nt];
        }

        bf16x4 curres[4];
#pragma unroll
        for (int nt = 0; nt < 4; ++nt) {
            curres[nt] = *(const bf16x4*)(&Xc[(nt * 16 + l15) * 72 + m0 + quad * 4]);
        }
        __syncthreads();                       // barrier B (Gt + skb visible)

        // ---- deferred res-conv weights (L2-hot reload per batch) ----
        bf16x8 aR0, aR1;
        {
            const __hip_bfloat16* wrA = wres + (size_t)(m0 + l15) * 64 + quad * 8;
            aR0 = *(const bf16x8*)(wrA);
            aR1 = *(const bf16x8*)(wrA + 32);
        }
        f32x4 biasR;
#pragma unroll
        for (int r = 0; r < 4; ++r) biasR[r] = rb[m0 + quad * 4 + r];

        f32x4 accR[4];
#pragma unroll
        for (int nt = 0; nt < 4; ++nt) accR[nt] = biasR;
#pragma unroll
        for (int ks = 0; ks < 2; ++ks) {
            const int kk = ks * 32 + quad * 8;
#pragma unroll
            for (int nt = 0; nt < 4; ++nt) {
                bf16x8 bx = *(const bf16x8*)(&Gt[(nt * 16 + l15) * 72 + kk]);
                accR[nt] = __builtin_amdgcn_mfma_f32_16x16x32_bf16(
                    (ks == 0) ? aR0 : aR1, bx, accR[nt], 0, 0, 0);
            }
        }

        __hip_bfloat16* nb = next + ((size_t)b * T_LEN + t0) * NCH;
#pragma unroll
        for (int nt = 0; nt < 4; ++nt) {
            int t = nt * 16 + l15;
            bf16x4 ov;
#pragma unroll
            for (int r = 0; r < 4; ++r) {
                ov[r] = f2bf(accR[nt][r] + bf2f(curres[nt][r]));
            }
            *(bf16x4*)(nb + t * NCH + m0 + quad * 4) = ov;
        }

        // ---- skip finalize: sum 4 wave-partials, one RMW per t ----
        if (tid < 64) {
            float tot = skb[tid] + skb[64 + tid] + skb[128 + tid] + skb[192 + tid];
            acc[(size_t)b * T_LEN + t0 + tid] += tot;
        }
        // next iteration's skb writes are after barrier A(b+1) -> no race
    }
}

// ---------------------------------------------------------------------------
// Last layer (17, d=256): GEMM1 + gate + skip only (res-conv output unused),
// fused finalize: out = acc + own skip + mix_b. No next write. (R2 config.)
// ---------------------------------------------------------------------------
__global__ __launch_bounds__(256, 2) void last_layer_kernel(
    const __hip_bfloat16* __restrict__ prev,   // [B][T][C]
    const float* __restrict__ acc,             // [B][T] (layers 0..16 summed)
    float* __restrict__ out,                   // [B][T] fp32
    const __hip_bfloat16* __restrict__ whid,   // [128][128] layer 17
    const float* __restrict__ hb,              // [128]
    const float* __restrict__ mw,              // [64] layer-17 mix slice
    const float* __restrict__ mix_b,           // [1]
    int d) {
    __shared__ __align__(16) __hip_bfloat16 Xp[64 * 72];
    __shared__ __align__(16) __hip_bfloat16 Xc[64 * 72];
    __shared__ float skb[4 * 64];

    const int t0   = blockIdx.x << 6;
    const int tid  = threadIdx.x;
    const int lane = tid & 63;
    const int w4   = tid >> 6;
    const int l15  = lane & 15;
    const int quad = lane >> 4;
    const int m0   = w4 * 16;
    const int rr = tid >> 3;
    const int co = (tid & 7) * 8;

    bf16x8 aT[4], aS[4];
    {
        const __hip_bfloat16* whT = whid + (size_t)(m0 + l15) * 128 + quad * 8;
        const __hip_bfloat16* whS = whT + 64 * 128;
#pragma unroll
        for (int k = 0; k < 4; ++k) {
            aT[k] = *(const bf16x8*)(whT + k * 32);
            aS[k] = *(const bf16x8*)(whS + k * 32);
        }
    }
    f32x4 biasT, biasS;
    float mwv[4];
#pragma unroll
    for (int r = 0; r < 4; ++r) {
        biasT[r] = hb[m0 + quad * 4 + r];
        biasS[r] = hb[64 + m0 + quad * 4 + r];
        mwv[r]   = mw[m0 + quad * 4 + r];
    }
    const float mb = mix_b[0];

    bf16x8 pc[2], pp[2];
#define LOAD_TILE(b)                                                          \
    do {                                                                      \
        const __hip_bfloat16* pb = prev + ((size_t)(b) * T_LEN + t0) * NCH;   \
        _Pragma("unroll")                                                     \
        for (int pass = 0; pass < 2; ++pass) {                                \
            int r = pass * 32 + rr;                                           \
            pc[pass] = *(const bf16x8*)(pb + r * NCH + co);                   \
            int tp = t0 + r - d;                                              \
            bf16x8 z = {0, 0, 0, 0, 0, 0, 0, 0};                              \
            pp[pass] = z;                                                     \
            if (tp >= 0)                                                      \
                pp[pass] = *(const bf16x8*)(prev +                            \
                    ((size_t)(b) * T_LEN + tp) * NCH + co);                   \
        }                                                                     \
    } while (0)

    LOAD_TILE(0);

#pragma unroll
    for (int b = 0; b < 4; ++b) {
#pragma unroll
        for (int pass = 0; pass < 2; ++pass) {
            int r = pass * 32 + rr;
            *(bf16x8*)(&Xc[r * 72 + co]) = pc[pass];
            *(bf16x8*)(&Xp[r * 72 + co]) = pp[pass];
        }
        __syncthreads();                       // barrier A

        if (b < 3) LOAD_TILE(b + 1);

        f32x4 accT[4], accS[4];
#pragma unroll
        for (int nt = 0; nt < 4; ++nt) { accT[nt] = biasT; accS[nt] = biasS; }
#pragma unroll
        for (int ks = 0; ks < 4; ++ks) {
            const __hip_bfloat16* srcb = (ks < 2) ? Xp : Xc;
            const int kk = (ks & 1) * 32 + quad * 8;
#pragma unroll
            for (int nt = 0; nt < 4; ++nt) {
                bf16x8 bx = *(const bf16x8*)(&srcb[(nt * 16 + l15) * 72 + kk]);
                accT[nt] = __builtin_amdgcn_mfma_f32_16x16x32_bf16(aT[ks], bx, accT[nt], 0, 0, 0);
                accS[nt] = __builtin_amdgcn_mfma_f32_16x16x32_bf16(aS[ks], bx, accS[nt], 0, 0, 0);
            }
        }

        // gate + skip partial (no Gt/GEMM2 needed for last layer)
#pragma unroll
        for (int nt = 0; nt < 4; ++nt) {
            float sv = 0.f;
#pragma unroll
            for (int r = 0; r < 4; ++r) {
                float e2 = __expf(2.f * accT[nt][r]);
                float th = 1.f - 2.f * __builtin_amdgcn_rcpf(e2 + 1.f);
                float sg = __builtin_amdgcn_rcpf(1.f + __expf(-accS[nt][r]));
                sv += mwv[r] * (th * sg);
            }
            sv += __shfl_xor(sv, 16, 64);
            sv += __shfl_xor(sv, 32, 64);
            if (quad == 0)
                skb[w4 * 64 + nt * 16 + l15] = sv;
        }
        __syncthreads();                       // barrier B

        if (tid < 64) {
            float tot = skb[tid] + skb[64 + tid] + skb[128 + tid] + skb[192 + tid];
            out[(size_t)b * T_LEN + t0 + tid] =
                acc[(size_t)b * T_LEN + t0 + tid] + tot + mb;
        }
    }
#undef LOAD_TILE
}

// ---------------------------------------------------------------------------
extern "C" void kernel_launch(void* const* d_in, const int* in_sizes, int n_in,
                              void* d_out, int out_size, void* d_ws, size_t ws_size,
                              hipStream_t stream) {
    const float* x     = (const float*)d_in[0];
    const float* in_w  = (const float*)d_in[1];
    const float* in_b  = (const float*)d_in[2];
    const float* hid_w = (const float*)d_in[3];  // [18][128][64][2]
    const float* hid_b = (const float*)d_in[4];  // [18][128]
    const float* res_w = (const float*)d_in[5];  // [18][64][64][1]
    const float* res_b = (const float*)d_in[6];  // [18][64]
    const float* mix_w = (const float*)d_in[7];  // [1152]
    const float* mix_b = (const float*)d_in[8];  // [1]
    float* out = (float*)d_out;

    // ws layout: actA 32M | actB 32M | acc 1M | whid 0.56M | wres 0.14M
    const size_t act_elems = 4ull * T_LEN * NCH;     // 16M bf16 = 32 MB
    __hip_bfloat16* actA = (__hip_bfloat16*)d_ws;
    __hip_bfloat16* actB = actA + act_elems;
    float* acc = (float*)(actB + act_elems);         // [B][T] = 1 MB
    __hip_bfloat16* whid = (__hip_bfloat16*)(acc + 4ull * T_LEN);
    __hip_bfloat16* wres = whid + (size_t)NLAYER * 128 * 128;

    hipMemsetAsync(acc, 0, 4ull * T_LEN * sizeof(float), stream);

    convert_weights_kernel<<<1152, 256, 0, stream>>>(hid_w, res_w, whid, wres);

    // P0: input conv + layers 0-5 (d=1..32) fused -> actA
    fused6_kernel<<<2048, 256, 0, stream>>>(
        x, actA, acc, whid, hid_b, wres, res_b, mix_w, in_w, in_b, 0, 1);

    // P1-P3: layers 6,7,8 (d=64,128,256)
    layer_mfma_kernel<<<1024, 256, 0, stream>>>(
        actA, actB, acc, whid + 6 * 16384, hid_b + 6 * 128,
        wres + 6 * 4096, res_b + 6 * 64, mix_w + 6 * 64, 64);
    layer_mfma_kernel<<<1024, 256, 0, stream>>>(
        actB, actA, acc, whid + 7 * 16384, hid_b + 7 * 128,
        wres + 7 * 4096, res_b + 7 * 64, mix_w + 7 * 64, 128);
    layer_mfma_kernel<<<1024, 256, 0, stream>>>(
        actA, actB, acc, whid + 8 * 16384, hid_b + 8 * 128,
        wres + 8 * 4096, res_b + 8 * 64, mix_w + 8 * 64, 256);

    // P4: layers 9-14 (d=1..32) fused -> actA
    fused6_kernel<<<2048, 256, 0, stream>>>(
        actB, actA, acc, whid, hid_b, wres, res_b, mix_w, in_w, in_b, 9, 0);

    // P5-P6: layers 15,16 (d=64,128)
    layer_mfma_kernel<<<1024, 256, 0, stream>>>(
        actA, actB, acc, whid + 15 * 16384, hid_b + 15 * 128,
        wres + 15 * 4096, res_b + 15 * 64, mix_w + 15 * 64, 64);
    layer_mfma_kernel<<<1024, 256, 0, stream>>>(
        actB, actA, acc, whid + 16 * 16384, hid_b + 16 * 128,
        wres + 16 * 4096, res_b + 16 * 64, mix_w + 16 * 64, 128);

    // P7: layer 17 (d=256) + finalize -> out
    last_layer_kernel<<<1024, 256, 0, stream>>>(
        actA, acc, out, whid + 17 * 16384, hid_b + 17 * 128,
        mix_w + 17 * 64, mix_b, 256);
}